// Round 2
// baseline (467.851 us; speedup 1.0000x reference)
//
#include <hip/hip_runtime.h>

using u16 = unsigned short;
using u32 = unsigned int;
using s16x8 = __attribute__((ext_vector_type(8))) short;
using bf16x8 = __attribute__((ext_vector_type(8))) __bf16;
using f32x4 = __attribute__((ext_vector_type(4))) float;

__device__ inline u16 f2bf(float f) {
  u32 u = __float_as_uint(f);
  u = (u + 0x7FFFu + ((u >> 16) & 1u)) >> 16;
  return (u16)u;
}

__device__ inline f32x4 mfma16(s16x8 a, s16x8 b, f32x4 c) {
  return __builtin_amdgcn_mfma_f32_16x16x32_bf16(
      __builtin_bit_cast(bf16x8, a), __builtin_bit_cast(bf16x8, b), c, 0, 0, 0);
}

// async global->LDS, 16B per lane; LDS dest = wave-uniform base + lane*16
__device__ inline void load_lds16(const void* g, void* l) {
  __builtin_amdgcn_global_load_lds(
      (const __attribute__((address_space(1))) void*)g,
      (__attribute__((address_space(3))) void*)l, 16, 0, 0);
}

// ---------------------------------------------------------------------------
// Generic cast fp32 -> bf16 (n must be a multiple of 1024)
// ---------------------------------------------------------------------------
__global__ __launch_bounds__(256) void cast_f32_bf16(
    const float* __restrict__ in, u16* __restrict__ out, int n) {
  int i = (blockIdx.x * 256 + threadIdx.x) * 4;
  if (i + 3 < n) {
    float4 f = *(const float4*)(in + i);
    ushort4 o;
    o.x = f2bf(f.x); o.y = f2bf(f.y); o.z = f2bf(f.z); o.w = f2bf(f.w);
    *(ushort4*)(out + i) = o;
  }
}

// ---------------------------------------------------------------------------
// bf16 transpose: in [rows][cols] -> out [cols][rows], per-batch (blockIdx.z)
// ---------------------------------------------------------------------------
__global__ __launch_bounds__(256) void transpose_bf16(
    const u16* __restrict__ in, u16* __restrict__ out, int rows, int cols) {
  __shared__ u16 tile[32][33];
  const size_t boff = (size_t)blockIdx.z * rows * cols;
  const u16* inb = in + boff;
  u16* outb = out + boff;
  const int c0 = blockIdx.x * 32, r0 = blockIdx.y * 32;
  const int tx = threadIdx.x & 31, ty = threadIdx.x >> 5;  // ty: 0..7
#pragma unroll
  for (int j = 0; j < 32; j += 8)
    tile[ty + j][tx] = inb[(size_t)(r0 + ty + j) * cols + c0 + tx];
  __syncthreads();
#pragma unroll
  for (int j = 0; j < 32; j += 8)
    outb[(size_t)(c0 + ty + j) * rows + r0 + tx] = tile[tx][ty + j];
}

// ---------------------------------------------------------------------------
// bf16 GEMM (projections), C[m,n] = sum_k A[m,k]*B[n,k] + bias[n], bf16 out.
// 128x128 tile, BK=32, 4 waves, 4x4 16x16x32 MFMAs per wave.
// ---------------------------------------------------------------------------
__global__ __launch_bounds__(256) void gemm_bt_bias(
    const u16* __restrict__ A, const u16* __restrict__ B, u16* __restrict__ C,
    const float* __restrict__ bias, int M, int N, int K) {
  const int m0 = blockIdx.y * 128;
  const int n0 = blockIdx.x * 128;
  const int tid = threadIdx.x;
  const int lane = tid & 63;
  const int wave = tid >> 6;
  const int wm = (wave >> 1) * 64;
  const int wn = (wave & 1) * 64;

  __shared__ u16 As[128 * 32];
  __shared__ u16 Bs[128 * 32];

  const int sr = lane >> 2;
  const int sc = (lane & 3) * 8;
  const int ch0 = wave * 2;

  f32x4 acc[4][4];
#pragma unroll
  for (int i = 0; i < 4; ++i)
#pragma unroll
    for (int j = 0; j < 4; ++j) acc[i][j] = 0.0f;

  const int fr = lane & 15;
  const int fk = (lane >> 4) * 8;

  for (int k0 = 0; k0 < K; k0 += 32) {
#pragma unroll
    for (int it = 0; it < 2; ++it) {
      const int ch = ch0 + it;
      const int row = ch * 16 + sr;
      load_lds16(A + (size_t)(m0 + row) * K + k0 + sc, &As[ch * 512]);
      load_lds16(B + (size_t)(n0 + row) * K + k0 + sc, &Bs[ch * 512]);
    }
    __syncthreads();
    s16x8 af[4], bfr[4];
#pragma unroll
    for (int i = 0; i < 4; ++i) {
      af[i]  = *(const s16x8*)&As[(wm + i * 16 + fr) * 32 + fk];
      bfr[i] = *(const s16x8*)&Bs[(wn + i * 16 + fr) * 32 + fk];
    }
#pragma unroll
    for (int mi = 0; mi < 4; ++mi)
#pragma unroll
      for (int ni = 0; ni < 4; ++ni)
        acc[mi][ni] = mfma16(af[mi], bfr[ni], acc[mi][ni]);
    __syncthreads();
  }

  const int er = (lane >> 4) * 4;
  const int ec = lane & 15;
#pragma unroll
  for (int mi = 0; mi < 4; ++mi)
#pragma unroll
    for (int ni = 0; ni < 4; ++ni) {
      const int col = n0 + wn + ni * 16 + ec;
      const float badd = bias[col];
#pragma unroll
      for (int i = 0; i < 4; ++i) {
        const int row = m0 + wm + mi * 16 + er + i;
        C[(size_t)row * N + col] = f2bf(acc[mi][ni][i] + badd);
      }
    }
}

// ---------------------------------------------------------------------------
// Flash cross-attention: out[b, q0:q0+32, 0:512] for one 32-row Q-tile.
// q: [B,S,D] bf16   k: [B,S,D] bf16   vT: [B,D,S] bf16   out: [B,S,D] fp32
// Block = 128 threads (2 waves); wave w owns q-rows [q0+16w, q0+16w+16).
// Streams keys in 16 chunks of 128; online softmax, lane-local C-layout stats.
// ---------------------------------------------------------------------------
__global__ __launch_bounds__(128, 2) void flash_attn(
    const u16* __restrict__ q, const u16* __restrict__ k,
    const u16* __restrict__ vT, float* __restrict__ out, float scale) {
  constexpr int S = 2048, D = 512;
  const int b = blockIdx.y;
  const int q0 = blockIdx.x * 32;
  const int tid = threadIdx.x;
  const int lane = tid & 63;
  const int wave = tid >> 6;
  const int fr = lane & 15;   // A-frag row / C-layout col
  const int fg = lane >> 4;   // 0..3
  const int er = fg * 4;      // C-layout row base

  // K tile [128 keys][64 d], granule(16B=8 elt) slot swizzled: slot=(gd+r)&7
  __shared__ alignas(16) u16 Ks[128 * 64];
  // V tile [64 d][128 keys], slot=(gk+r)&15
  __shared__ alignas(16) u16 Vs[64 * 128];
  // P per-wave [16 rows][128 keys], padded to 136 (stride 272B = 17*16B)
  __shared__ alignas(16) u16 Ps[2 * 16 * 136];

  const u16* qrow = q + ((size_t)b * S + q0 + wave * 16 + fr) * D;
  const u16* kbase = k + (size_t)b * S * D;
  const u16* vbase = vT + (size_t)b * D * S;
  u16* Pw = &Ps[wave * 16 * 136];

  f32x4 acc[32];
#pragma unroll
  for (int i = 0; i < 32; ++i) acc[i] = 0.0f;
  float m[4], l[4];
#pragma unroll
  for (int i = 0; i < 4; ++i) { m[i] = -3e38f; l[i] = 0.0f; }

  for (int kc = 0; kc < S; kc += 128) {
    // ---- S = Q K^T for [32 q-rows x 128 keys], contract over D=512 ----
    f32x4 sacc[8];
#pragma unroll
    for (int i = 0; i < 8; ++i) sacc[i] = 0.0f;

    for (int dk = 0; dk < D; dk += 64) {
      // stage Ks: 1024 granules, 8 per thread
#pragma unroll
      for (int c = 0; c < 8; ++c) {
        const int g = c * 128 + tid;
        const int r = g >> 3, s = g & 7;
        const int gd = (s - r) & 7;
        load_lds16(kbase + (size_t)(kc + r) * D + dk + gd * 8,
                   (char*)Ks + (c * 128 + wave * 64) * 16);
      }
      // Q A-frags for this d-chunk (global, L2-hot; drained by the barrier)
      s16x8 qf0 = *(const s16x8*)(qrow + dk + fg * 8);
      s16x8 qf1 = *(const s16x8*)(qrow + dk + 32 + fg * 8);
      __syncthreads();
#pragma unroll
      for (int nt = 0; nt < 8; ++nt) {
        const int r = nt * 16 + fr;
        const int s0 = (fg + r) & 7;
        const int s1 = (4 + fg + r) & 7;
        s16x8 kf0 = *(const s16x8*)&Ks[r * 64 + s0 * 8];
        sacc[nt] = mfma16(qf0, kf0, sacc[nt]);
        s16x8 kf1 = *(const s16x8*)&Ks[r * 64 + s1 * 8];
        sacc[nt] = mfma16(qf1, kf1, sacc[nt]);
      }
      __syncthreads();
    }

    // ---- online softmax (C-layout: row er+i, col nt*16+fr) ----
    float mx[4];
#pragma unroll
    for (int i = 0; i < 4; ++i) mx[i] = -3e38f;
#pragma unroll
    for (int nt = 0; nt < 8; ++nt)
#pragma unroll
      for (int i = 0; i < 4; ++i) mx[i] = fmaxf(mx[i], sacc[nt][i]);
#pragma unroll
    for (int i = 0; i < 4; ++i) {
#pragma unroll
      for (int o = 1; o < 16; o <<= 1) mx[i] = fmaxf(mx[i], __shfl_xor(mx[i], o));
    }
    float mn[4], alpha[4], rs[4];
#pragma unroll
    for (int i = 0; i < 4; ++i) {
      mn[i] = fmaxf(m[i], mx[i] * scale);
      alpha[i] = __expf(m[i] - mn[i]);
      m[i] = mn[i];
      rs[i] = 0.0f;
    }
#pragma unroll
    for (int nt = 0; nt < 8; ++nt)
#pragma unroll
      for (int i = 0; i < 4; ++i) {
        const float p = __expf(sacc[nt][i] * scale - mn[i]);
        rs[i] += p;
        Pw[(er + i) * 136 + nt * 16 + fr] = f2bf(p);
      }
#pragma unroll
    for (int i = 0; i < 4; ++i) {
#pragma unroll
      for (int o = 1; o < 16; o <<= 1) rs[i] += __shfl_xor(rs[i], o);
      l[i] = l[i] * alpha[i] + rs[i];
    }
    // rescale O accumulator
#pragma unroll
    for (int dt = 0; dt < 32; ++dt)
#pragma unroll
      for (int i = 0; i < 4; ++i) acc[dt][i] *= alpha[i];

    // ---- O += P V : contract over 128 keys, output 512 d ----
    for (int dv = 0; dv < D; dv += 64) {
#pragma unroll
      for (int c = 0; c < 8; ++c) {
        const int g = c * 128 + tid;
        const int r = g >> 4, s = g & 15;
        const int gk = (s - r) & 15;
        load_lds16(vbase + (size_t)(dv + r) * S + kc + gk * 8,
                   (char*)Vs + (c * 128 + wave * 64) * 16);
      }
      __syncthreads();
#pragma unroll
      for (int ks = 0; ks < 4; ++ks) {
        s16x8 pf = *(const s16x8*)&Pw[fr * 136 + ks * 32 + fg * 8];
#pragma unroll
        for (int nt = 0; nt < 4; ++nt) {
          const int r = nt * 16 + fr;
          const int slot = (ks * 4 + fg + r) & 15;
          s16x8 vf = *(const s16x8*)&Vs[r * 128 + slot * 8];
          const int dt = (dv >> 4) + nt;
          acc[dt] = mfma16(pf, vf, acc[dt]);
        }
      }
      __syncthreads();
    }
  }

  // ---- epilogue: normalize by 1/l, store fp32 ----
  float linv[4];
#pragma unroll
  for (int i = 0; i < 4; ++i) linv[i] = 1.0f / l[i];
  float* ob = out + ((size_t)b * S + q0 + wave * 16) * D;
#pragma unroll
  for (int dt = 0; dt < 32; ++dt)
#pragma unroll
    for (int i = 0; i < 4; ++i)
      ob[(size_t)(er + i) * D + dt * 16 + fr] = acc[dt][i] * linv[i];
}

// ---------------------------------------------------------------------------
extern "C" void kernel_launch(void* const* d_in, const int* in_sizes, int n_in,
                              void* d_out, int out_size, void* d_ws, size_t ws_size,
                              hipStream_t stream) {
  constexpr int B = 8, S = 2048, D = 512;
  constexpr size_t MS = (size_t)B * S;

  const float* x1 = (const float*)d_in[0];
  const float* x2 = (const float*)d_in[1];
  const float* Wq = (const float*)d_in[2];
  const float* bq = (const float*)d_in[3];
  const float* Wk = (const float*)d_in[4];
  const float* bk = (const float*)d_in[5];
  const float* Wv = (const float*)d_in[6];
  const float* bv = (const float*)d_in[7];
  float* out = (float*)d_out;

  // workspace (bf16 elements). vT aliases x1b (dead after q-projection).
  u16* x1b = (u16*)d_ws;            // MS*D
  u16* x2b = x1b + MS * D;          // MS*D
  u16* Wqb = x2b + MS * D;          // D*D
  u16* Wkb = Wqb + (size_t)D * D;
  u16* Wvb = Wkb + (size_t)D * D;
  u16* qb  = Wvb + (size_t)D * D;   // MS*D
  u16* kb  = qb + MS * D;           // MS*D
  u16* vb  = kb + MS * D;           // MS*D
  u16* vTb = x1b;                   // alias: [B][D][S]

  dim3 blk(256);

  cast_f32_bf16<<<(MS * D) / 1024, blk, 0, stream>>>(x1, x1b, MS * D);
  cast_f32_bf16<<<(MS * D) / 1024, blk, 0, stream>>>(x2, x2b, MS * D);
  cast_f32_bf16<<<(D * D) / 1024, blk, 0, stream>>>(Wq, Wqb, D * D);
  cast_f32_bf16<<<(D * D) / 1024, blk, 0, stream>>>(Wk, Wkb, D * D);
  cast_f32_bf16<<<(D * D) / 1024, blk, 0, stream>>>(Wv, Wvb, D * D);

  gemm_bt_bias<<<dim3(4, 128), blk, 0, stream>>>(x1b, Wqb, qb, bq, 16384, 512, 512);
  gemm_bt_bias<<<dim3(4, 128), blk, 0, stream>>>(x2b, Wkb, kb, bk, 16384, 512, 512);
  gemm_bt_bias<<<dim3(4, 128), blk, 0, stream>>>(x2b, Wvb, vb, bv, 16384, 512, 512);

  transpose_bf16<<<dim3(512 / 32, 2048 / 32, B), blk, 0, stream>>>(vb, vTb, 2048, 512);

  flash_attn<<<dim3(S / 32, B), dim3(128), 0, stream>>>(
      qb, kb, vTb, out, 1.0f / (float)D);
}

// Round 3
// 287.153 us; speedup vs baseline: 1.6293x; 1.6293x over previous
//
#include <hip/hip_runtime.h>

using u16 = unsigned short;
using u32 = unsigned int;
using s16x8 = __attribute__((ext_vector_type(8))) short;
using bf16x8 = __attribute__((ext_vector_type(8))) __bf16;
using f32x4 = __attribute__((ext_vector_type(4))) float;

__device__ inline u16 f2bf(float f) {
  u32 u = __float_as_uint(f);
  u = (u + 0x7FFFu + ((u >> 16) & 1u)) >> 16;
  return (u16)u;
}

__device__ inline f32x4 mfma16(s16x8 a, s16x8 b, f32x4 c) {
  return __builtin_amdgcn_mfma_f32_16x16x32_bf16(
      __builtin_bit_cast(bf16x8, a), __builtin_bit_cast(bf16x8, b), c, 0, 0, 0);
}

// async global->LDS, 16B/lane; LDS dest = wave-uniform base + lane*16
__device__ inline void load_lds16(const void* g, void* l) {
  __builtin_amdgcn_global_load_lds(
      (const __attribute__((address_space(1))) void*)g,
      (__attribute__((address_space(3))) void*)l, 16, 0, 0);
}

// ---------------------------------------------------------------------------
__global__ __launch_bounds__(256) void cast_f32_bf16(
    const float* __restrict__ in, u16* __restrict__ out, int n) {
  int i = (blockIdx.x * 256 + threadIdx.x) * 4;
  if (i + 3 < n) {
    float4 f = *(const float4*)(in + i);
    ushort4 o;
    o.x = f2bf(f.x); o.y = f2bf(f.y); o.z = f2bf(f.z); o.w = f2bf(f.w);
    *(ushort4*)(out + i) = o;
  }
}

// cast the three weight matrices in one launch (blockIdx.y selects)
__global__ __launch_bounds__(256) void cast_w3(
    const float* __restrict__ a, const float* __restrict__ b,
    const float* __restrict__ c, u16* __restrict__ oa, u16* __restrict__ ob,
    u16* __restrict__ oc) {
  const float* in = blockIdx.y == 0 ? a : (blockIdx.y == 1 ? b : c);
  u16* out = blockIdx.y == 0 ? oa : (blockIdx.y == 1 ? ob : oc);
  int i = (blockIdx.x * 256 + threadIdx.x) * 4;
  float4 f = *(const float4*)(in + i);
  ushort4 o;
  o.x = f2bf(f.x); o.y = f2bf(f.y); o.z = f2bf(f.z); o.w = f2bf(f.w);
  *(ushort4*)(out + i) = o;
}

__global__ __launch_bounds__(256) void zero_f32(float* __restrict__ p, int n) {
  int i = blockIdx.x * 256 + threadIdx.x;
  if (i < n) p[i] = 0.0f;
}

__global__ __launch_bounds__(256) void recip_f32(float* __restrict__ p, int n) {
  int i = blockIdx.x * 256 + threadIdx.x;
  if (i < n) p[i] = 1.0f / p[i];
}

// ---------------------------------------------------------------------------
// bf16 GEMM, C[m,n] = sum_k A[m,k]*B[n,k]  (both operands K-contiguous).
// 128x128 tile, BK=64, 4 waves (2x2), 4x4 16x16x32 MFMAs x2 k-steps per iter.
// LDS granule-slot XOR swizzle (slot = g ^ (row&7)) applied via the staging
// SOURCE address, keeping the wave-uniform-base global_load_lds contract.
// EPI 0: bf16 out = acc + bias[n]                       (q/k projection)
// EPI 1: bf16 out transposed to vT[b][d][s] (+bias)     (v projection)
// EPI 2: bf16 out = exp(acc*scale), atomic row sums -> lsum  (scores)
// EPI 3: fp32 out = acc * aux[row] (aux = 1/l)          (PV)
// Requires M%128==0, N%128==0, K%64==0.
// ---------------------------------------------------------------------------
template <int EPI>
__global__ __launch_bounds__(256) void gemm64(
    const u16* __restrict__ A, const u16* __restrict__ B, void* __restrict__ C,
    const float* __restrict__ aux, float* __restrict__ lsum, float scale,
    int M, int N, int K, long sA, long sB, long sC) {
  const int bz = blockIdx.z;
  const u16* Ab = A + (size_t)bz * sA;
  const u16* Bb = B + (size_t)bz * sB;
  const int m0 = blockIdx.y * 128;
  const int n0 = blockIdx.x * 128;
  const int tid = threadIdx.x;
  const int lane = tid & 63;
  const int wave = tid >> 6;
  const int wm = (wave >> 1) * 64;
  const int wn = (wave & 1) * 64;

  __shared__ u16 As[128 * 64];
  __shared__ u16 Bs[128 * 64];

  // staging: 16 chunks/operand of 1024B (8 rows x 64 cols); wave w: chunks 4w..4w+3
  const int sr = lane >> 3;        // row within 8-row chunk
  const int gd = (lane & 7) ^ sr;  // swizzled source granule (16B units)
  const int ch0 = wave * 4;

  f32x4 acc[4][4];
#pragma unroll
  for (int i = 0; i < 4; ++i)
#pragma unroll
    for (int j = 0; j < 4; ++j) acc[i][j] = 0.0f;

  const int fr = lane & 15;
  const int fg = lane >> 4;  // 0..3

  for (int k0 = 0; k0 < K; k0 += 64) {
#pragma unroll
    for (int it = 0; it < 4; ++it) {
      const int ch = ch0 + it;
      const int row = ch * 8 + sr;
      load_lds16(Ab + (size_t)(m0 + row) * K + k0 + gd * 8, &As[ch * 512]);
      load_lds16(Bb + (size_t)(n0 + row) * K + k0 + gd * 8, &Bs[ch * 512]);
    }
    __syncthreads();
#pragma unroll
    for (int s = 0; s < 2; ++s) {
      const int slot = ((s * 4 + fg) ^ (fr & 7)) * 8;
      s16x8 af[4], bfr[4];
#pragma unroll
      for (int i = 0; i < 4; ++i) {
        af[i]  = *(const s16x8*)&As[(wm + i * 16 + fr) * 64 + slot];
        bfr[i] = *(const s16x8*)&Bs[(wn + i * 16 + fr) * 64 + slot];
      }
#pragma unroll
      for (int mi = 0; mi < 4; ++mi)
#pragma unroll
        for (int ni = 0; ni < 4; ++ni)
          acc[mi][ni] = mfma16(af[mi], bfr[ni], acc[mi][ni]);
    }
    __syncthreads();
  }

  // C/D layout: col = lane&15, row = (lane>>4)*4 + i
  const int er = fg * 4;
  const int ec = fr;

  if (EPI == 0) {
    u16* Cb = (u16*)C;
#pragma unroll
    for (int mi = 0; mi < 4; ++mi)
#pragma unroll
      for (int ni = 0; ni < 4; ++ni) {
        const int col = n0 + wn + ni * 16 + ec;
        const float badd = aux[col];
#pragma unroll
        for (int i = 0; i < 4; ++i) {
          const int row = m0 + wm + mi * 16 + er + i;
          Cb[(size_t)row * N + col] = f2bf(acc[mi][ni][i] + badd);
        }
      }
  } else if (EPI == 1) {
    // transposed store: token row t -> vT[t>>11][col][t&2047]
    u16* Cv = (u16*)C;
#pragma unroll
    for (int mi = 0; mi < 4; ++mi)
#pragma unroll
      for (int ni = 0; ni < 4; ++ni) {
        const int col = n0 + wn + ni * 16 + ec;
        const float badd = aux[col];
        const int row0 = m0 + wm + mi * 16 + er;
        ushort4 o;
        o.x = f2bf(acc[mi][ni][0] + badd);
        o.y = f2bf(acc[mi][ni][1] + badd);
        o.z = f2bf(acc[mi][ni][2] + badd);
        o.w = f2bf(acc[mi][ni][3] + badd);
        const size_t addr = (size_t)(row0 >> 11) * (512 * 2048) +
                            (size_t)col * 2048 + (row0 & 2047);
        *(ushort4*)&Cv[addr] = o;
      }
  } else if (EPI == 2) {
    u16* Cb = (u16*)C + (size_t)bz * sC;
#pragma unroll
    for (int mi = 0; mi < 4; ++mi) {
      float rs[4] = {0.0f, 0.0f, 0.0f, 0.0f};
#pragma unroll
      for (int ni = 0; ni < 4; ++ni) {
        const int col = n0 + wn + ni * 16 + ec;
#pragma unroll
        for (int i = 0; i < 4; ++i) {
          const float p = __expf(acc[mi][ni][i] * scale);
          rs[i] += p;
          Cb[(size_t)(m0 + wm + mi * 16 + er + i) * N + col] = f2bf(p);
        }
      }
#pragma unroll
      for (int i = 0; i < 4; ++i) {
        rs[i] += __shfl_xor(rs[i], 1);
        rs[i] += __shfl_xor(rs[i], 2);
        rs[i] += __shfl_xor(rs[i], 4);
        rs[i] += __shfl_xor(rs[i], 8);
      }
      if (ec == 0) {
#pragma unroll
        for (int i = 0; i < 4; ++i)
          atomicAdd(&lsum[(size_t)bz * M + m0 + wm + mi * 16 + er + i], rs[i]);
      }
    }
  } else {  // EPI == 3
    float* Cb = (float*)C + (size_t)bz * sC;
#pragma unroll
    for (int mi = 0; mi < 4; ++mi)
#pragma unroll
      for (int i = 0; i < 4; ++i) {
        const int row = m0 + wm + mi * 16 + er + i;
        const float li = aux[(size_t)bz * M + row];
#pragma unroll
        for (int ni = 0; ni < 4; ++ni) {
          const int col = n0 + wn + ni * 16 + ec;
          Cb[(size_t)row * N + col] = acc[mi][ni][i] * li;
        }
      }
  }
}

// ---------------------------------------------------------------------------
extern "C" void kernel_launch(void* const* d_in, const int* in_sizes, int n_in,
                              void* d_out, int out_size, void* d_ws, size_t ws_size,
                              hipStream_t stream) {
  constexpr int B = 8, S = 2048, D = 512;
  constexpr size_t MS = (size_t)B * S;  // 16384 token rows

  const float* x1 = (const float*)d_in[0];
  const float* x2 = (const float*)d_in[1];
  const float* Wq = (const float*)d_in[2];
  const float* bq = (const float*)d_in[3];
  const float* Wk = (const float*)d_in[4];
  const float* bk = (const float*)d_in[5];
  const float* Wv = (const float*)d_in[6];
  const float* bv = (const float*)d_in[7];
  float* out = (float*)d_out;

  // workspace (u16 elements unless noted)
  u16* x1b = (u16*)d_ws;              // MS*D
  u16* x2b = x1b + MS * D;            // MS*D
  u16* Wqb = x2b + MS * D;            // D*D
  u16* Wkb = Wqb + (size_t)D * D;
  u16* Wvb = Wkb + (size_t)D * D;
  u16* qb  = Wvb + (size_t)D * D;     // MS*D
  u16* kb  = qb + MS * D;             // MS*D
  u16* vTb = kb + MS * D;             // MS*D   [B][D][S]
  u16* Sc  = vTb + MS * D;            // B*S*S  (67 MB)
  float* lbuf = (float*)(Sc + (size_t)B * S * S);  // B*S fp32 row sums

  dim3 blk(256);

  cast_f32_bf16<<<(MS * D) / 1024, blk, 0, stream>>>(x1, x1b, MS * D);
  cast_f32_bf16<<<(MS * D) / 1024, blk, 0, stream>>>(x2, x2b, MS * D);
  cast_w3<<<dim3((D * D) / 1024, 3), blk, 0, stream>>>(Wq, Wk, Wv, Wqb, Wkb, Wvb);
  zero_f32<<<(B * S) / 256, blk, 0, stream>>>(lbuf, B * S);

  // projections: M=16384, N=512, K=512
  gemm64<0><<<dim3(4, 128, 1), blk, 0, stream>>>(
      x1b, Wqb, qb, bq, nullptr, 0.0f, 16384, 512, 512, 0, 0, 0);
  gemm64<0><<<dim3(4, 128, 1), blk, 0, stream>>>(
      x2b, Wkb, kb, bk, nullptr, 0.0f, 16384, 512, 512, 0, 0, 0);
  gemm64<1><<<dim3(4, 128, 1), blk, 0, stream>>>(
      x2b, Wvb, vTb, bv, nullptr, 0.0f, 16384, 512, 512, 0, 0, 0);

  // scores: per batch M=2048, N=2048, K=512; epilogue exp(s/D) + row sums
  gemm64<2><<<dim3(16, 16, B), blk, 0, stream>>>(
      qb, kb, Sc, nullptr, lbuf, 1.0f / (float)D, 2048, 2048, 512,
      (long)S * D, (long)S * D, (long)S * S);

  recip_f32<<<(B * S) / 256, blk, 0, stream>>>(lbuf, B * S);

  // PV: per batch M=2048, N=512, K=2048; epilogue scale by 1/l, fp32 out
  gemm64<3><<<dim3(4, 16, B), blk, 0, stream>>>(
      Sc, vTb, out, lbuf, nullptr, 0.0f, 2048, 512, 2048,
      (long)S * S, (long)D * S, (long)S * D);
}